// Round 12
// baseline (488.954 us; speedup 1.0000x reference)
//
#include <hip/hip_runtime.h>
#include <hip/hip_bf16.h>

#define NEG_SLOPE 0.2f
#define EPS_BN 1e-5f
#define EPS_SM 1e-16f
#define CAP 128  // padded adjacency row capacity (Poisson(17): P(deg>128) ~ 0; clamped anyway)

typedef __bf16 bf16x8 __attribute__((ext_vector_type(8)));
typedef __bf16 bf16x4 __attribute__((ext_vector_type(4)));
typedef float floatx4 __attribute__((ext_vector_type(4)));

__device__ __forceinline__ float leaky(float x) { return x > 0.f ? x : NEG_SLOPE * x; }

// ---- init: block 0 = edge dtype detect (no atomics, no pre-zero); blocks 1.. = zero ----
__global__ void k_init(const int* __restrict__ ei, int* __restrict__ flag,
                       int* __restrict__ zbase, int zwords, int e) {
    if (blockIdx.x == 0) {
        __shared__ int cnt_s[256];
        int i = threadIdx.x;  // pairs 0..255
        int nz = (2 * i + 1 < 2 * e && ei[2 * i + 1] != 0) ? 1 : 0;
        cnt_s[i] = nz;
        __syncthreads();
        for (int off = 128; off > 0; off >>= 1) {
            if (i < off) cnt_s[i] += cnt_s[i + off];
            __syncthreads();
        }
        if (i == 0) *flag = (cnt_s[0] < 128) ? 1 : 0;  // 1 => int64 layout
        return;
    }
    int g = (blockIdx.x - 1) * 256 + threadIdx.x;
    int stride = (gridDim.x - 1) * 256;
    for (int k = g; k < zwords; k += stride) zbase[k] = 0;
}

// ---- hist + DIRECT scatter (rank from atomic) + weight convert in grid tail ----
__global__ void k_hist_wconv(const int* __restrict__ ei, const int* __restrict__ flag,
                             int* __restrict__ deg, int* __restrict__ col, int e, int ebase,
                             const float* __restrict__ W1, __bf16* __restrict__ Wb1,
                             const float* __restrict__ W2, __bf16* __restrict__ Wb2,
                             const float* __restrict__ W3, __bf16* __restrict__ Wb3) {
    int g = threadIdx.x + blockIdx.x * blockDim.x;
    if (g < e) {
        bool is64 = (*flag) != 0;
        int s = is64 ? ei[2 * g] : ei[g];
        int d = is64 ? ei[2 * (e + g)] : ei[e + g];
        int r = atomicAdd(&deg[d], 1);
        if (r < CAP) col[((size_t)d << 7) + r] = s;
    } else {
        int idx = g - ebase;
        if (idx >= 0 && idx < 32768) {          // W1: K=128, M=256
            int mm = idx >> 7, kk = idx & 127;
            Wb1[idx] = (__bf16)W1[(size_t)kk * 256 + mm];
        } else if (idx < 65536) {               // W2: K=256, M=128
            int i2 = idx - 32768;
            int mm = i2 >> 8, kk = i2 & 255;
            Wb2[i2] = (__bf16)W2[(size_t)kk * 128 + mm];
        } else if (idx < 81920) {               // W3: K=128, M=128
            int i3 = idx - 65536;
            int mm = i3 >> 7, kk = i3 & 127;
            Wb3[i3] = (__bf16)W3[(size_t)kk * 128 + mm];
        }
    }
}

// ---- bf16 MFMA GEMM, 128-row x (NT*16)-col tile, inline BN prep + attn dots.
//      Each block covers ONE complete head -> attn dots are complete: plain stores.
template <int K, int LC, bool BF16IN, int NT>
__global__ __launch_bounds__(256) void k_gemm(const void* __restrict__ Ain,
                                              const __bf16* __restrict__ Bt,
                                              __bf16* __restrict__ Cb, int n, int M,
                                              const float* __restrict__ bnsums,
                                              const float* __restrict__ gam,
                                              const float* __restrict__ bet,
                                              const float* __restrict__ att_s,
                                              const float* __restrict__ att_d,
                                              float* __restrict__ asrc,
                                              float* __restrict__ adst) {
    __shared__ __align__(16) __bf16 As[128][72];
    __shared__ __align__(16) __bf16 Bs[NT * 16][72];
    __shared__ float sc_lds[K], sh_lds[K];
    const int row0 = blockIdx.y * 128, col0 = blockIdx.x * (NT * 16);
    const int lane = threadIdx.x & 63, w = threadIdx.x >> 6;
    const int m = lane & 15, quad = lane >> 4;

    if (bnsums) {
        for (int c = threadIdx.x; c < K; c += 256) {
            float mean = bnsums[c] / n;
            float var = bnsums[256 + c] / n - mean * mean;
            float sc = gam[c] * rsqrtf(var + EPS_BN);
            sc_lds[c] = sc;
            sh_lds[c] = bet[c] - mean * sc;
        }
        __syncthreads();
    }

    floatx4 acc[2][NT];
#pragma unroll
    for (int i = 0; i < 2; ++i)
#pragma unroll
        for (int j = 0; j < NT; ++j) acc[i][j] = (floatx4)0.f;

    const int sr = threadIdx.x >> 1;        // A-stage: 0..127
    const int sk = (threadIdx.x & 1) * 32;

    for (int kc = 0; kc < K; kc += 64) {
        {
            int grow = row0 + sr;
            if (grow < n) {
                if (BF16IN) {
                    const __bf16* p = (const __bf16*)Ain + (size_t)grow * K + kc + sk;
#pragma unroll
                    for (int q = 0; q < 4; ++q) {
                        bf16x8 vv = *reinterpret_cast<const bf16x8*>(p + q * 8);
                        if (bnsums) {
                            int c = kc + sk + q * 8;
                            bf16x8 r;
#pragma unroll
                            for (int e2 = 0; e2 < 8; ++e2)
                                r[e2] = (__bf16)((float)vv[e2] * sc_lds[c + e2] + sh_lds[c + e2]);
                            vv = r;
                        }
                        *reinterpret_cast<bf16x8*>(&As[sr][sk + q * 8]) = vv;
                    }
                } else {
                    const float* p = (const float*)Ain + (size_t)grow * K + kc + sk;
#pragma unroll
                    for (int q = 0; q < 8; ++q) {
                        float4 v = *reinterpret_cast<const float4*>(p + q * 4);
                        bf16x4 cv = {(__bf16)v.x, (__bf16)v.y, (__bf16)v.z, (__bf16)v.w};
                        *reinterpret_cast<bf16x4*>(&As[sr][sk + q * 4]) = cv;
                    }
                }
            } else {
#pragma unroll
                for (int q = 0; q < 4; ++q)
                    *reinterpret_cast<bf16x8*>(&As[sr][sk + q * 8]) = (bf16x8)(__bf16)0.f;
            }
        }
        if (NT == 8) {
            const __bf16* p = Bt + (size_t)(col0 + sr) * K + kc + sk;
#pragma unroll
            for (int q = 0; q < 4; ++q)
                *reinterpret_cast<bf16x8*>(&Bs[sr][sk + q * 8]) =
                    *reinterpret_cast<const bf16x8*>(p + q * 8);
        } else {  // NT==4: 64 B-rows, 16 bf16 per thread
            int sr4 = threadIdx.x >> 2, sk4 = (threadIdx.x & 3) * 16;
            const __bf16* p = Bt + (size_t)(col0 + sr4) * K + kc + sk4;
            *reinterpret_cast<bf16x8*>(&Bs[sr4][sk4]) = *reinterpret_cast<const bf16x8*>(p);
            *reinterpret_cast<bf16x8*>(&Bs[sr4][sk4 + 8]) = *reinterpret_cast<const bf16x8*>(p + 8);
        }
        __syncthreads();
#pragma unroll
        for (int ks = 0; ks < 64; ks += 32) {
            bf16x8 a0 = *reinterpret_cast<const bf16x8*>(&As[w * 32 + m][ks + quad * 8]);
            bf16x8 a1 = *reinterpret_cast<const bf16x8*>(&As[w * 32 + 16 + m][ks + quad * 8]);
#pragma unroll
            for (int nt = 0; nt < NT; ++nt) {
                bf16x8 b = *reinterpret_cast<const bf16x8*>(&Bs[nt * 16 + m][ks + quad * 8]);
                acc[0][nt] = __builtin_amdgcn_mfma_f32_16x16x32_bf16(a0, b, acc[0][nt], 0, 0, 0);
                acc[1][nt] = __builtin_amdgcn_mfma_f32_16x16x32_bf16(a1, b, acc[1][nt], 0, 0, 0);
            }
        }
        __syncthreads();
    }
#pragma unroll
    for (int mt = 0; mt < 2; ++mt)
#pragma unroll
        for (int nt = 0; nt < NT; ++nt)
#pragma unroll
            for (int r = 0; r < 4; ++r) {
                int row = row0 + w * 32 + mt * 16 + quad * 4 + r;
                if (row < n) Cb[(size_t)row * M + col0 + nt * 16 + m] = (__bf16)acc[mt][nt][r];
            }
    // fused attention dots (single complete head per block -> plain store)
    {
        float asv[NT], adv[NT];
#pragma unroll
        for (int nt = 0; nt < NT; ++nt) {
            int c = col0 + nt * 16 + m;
            asv[nt] = att_s[c];
            adv[nt] = att_d[c];
        }
        const int h = (col0 >> LC) & 1;
#pragma unroll
        for (int mt = 0; mt < 2; ++mt)
#pragma unroll
            for (int r = 0; r < 4; ++r) {
                int row = row0 + w * 32 + mt * 16 + quad * 4 + r;
                float pa = 0.f, pb = 0.f;
#pragma unroll
                for (int nt = 0; nt < NT; ++nt) {
                    float v = acc[mt][nt][r];
                    pa += v * asv[nt];
                    pb += v * adv[nt];
                }
#pragma unroll
                for (int off = 1; off <= 8; off <<= 1) {
                    pa += __shfl_xor(pa, off);
                    pb += __shfl_xor(pb, off);
                }
                if (m == 0 && row < n) {
                    asrc[2 * row + h] = pa;
                    adst[2 * row + h] = pb;
                }
            }
    }
}

// ---- GAT aggregation: grouped gather, 4 slots in flight, padded-CSR.
//      FINAL: fuses the output linear (exact fp32) -> writes d_out[n,64] directly.
template <int C, bool OUTBF16, bool FINAL>
__global__ __launch_bounds__(256) void k_agg(const __bf16* __restrict__ xh,
                                             const float* __restrict__ asrc,
                                             const float* __restrict__ adst,
                                             const int* __restrict__ degv,
                                             const int* __restrict__ col,
                                             const float* __restrict__ bias,
                                             void* __restrict__ outv, int n,
                                             const float* __restrict__ lw,
                                             const float* __restrict__ lb) {
    constexpr int F = 2 * C;          // bf16 per row (256 or 128)
    constexpr int G = F / 8;          // lanes per edge (32 or 16)
    constexpr int NG = 64 / G;        // edges per wave-step (2 or 4)
    constexpr int GSH = (G == 32) ? 5 : 4;
    __shared__ float4 slots[4][80];   // 64 + 16 zero-pad for 4-deep unroll overrun
    __shared__ float lwt[FINAL ? 64 : 1][FINAL ? 129 : 1];  // lwt[j][c] = lw[c][j]
    __shared__ float hbuf[FINAL ? 4 : 1][FINAL ? 128 : 1];
    const int widx = threadIdx.x >> 6;
    const int node = blockIdx.x * 4 + widx;
    const int lane = threadIdx.x & 63;
    if constexpr (FINAL) {
        // stage lw transposed: [64][129] fp32; bank = (j + c) % 32 -> 2-way only
        for (int idx = threadIdx.x; idx < 8192; idx += 256) {
            int k = idx >> 6, mm = idx & 63;
            lwt[mm][k] = lw[(size_t)k * 64 + mm];
        }
        __syncthreads();
    }
    if (node >= n) return;
    const int t = lane & (G - 1);
    const int g = lane >> GSH;
    const bool h1 = (t * 8) >= C;
    if (lane >= 48) slots[widx][lane + 16] = make_float4(0.f, 0.f, 0.f, 0.f);
    const int* crow = col + ((size_t)node << 7);
    const int deg = min(degv[node], CAP);
    const float2 adv = *reinterpret_cast<const float2*>(adst + 2 * node);
    const float2 asv = *reinterpret_cast<const float2*>(asrc + 2 * node);
    const float es0 = leaky(asv.x + adv.x), es1 = leaky(asv.y + adv.y);
    float acc[8] = {};
    float d0 = 0.f, d1 = 0.f;
    for (int base = 0; base < deg; base += 64) {
        const int cnt = min(64, deg - base);
        float4 sv = make_float4(0.f, 0.f, 0.f, 0.f);
        if (lane < cnt) {
            int s = crow[base + lane];
            float2 av = *reinterpret_cast<const float2*>(asrc + 2 * s);
            float w0 = __expf(leaky(av.x + adv.x));
            float w1 = __expf(leaky(av.y + adv.y));
            d0 += w0; d1 += w1;
            sv = make_float4(__int_as_float(s * (F * 2)), w0, w1, 0.f);
        }
        slots[widx][lane] = sv;  // wave-synchronous; zero weights beyond cnt
        for (int j = g; j < cnt; j += 4 * NG) {
            float4 s0 = slots[widx][j];
            float4 s1 = slots[widx][j + NG];
            float4 s2 = slots[widx][j + 2 * NG];
            float4 s3 = slots[widx][j + 3 * NG];
            const char* xb = (const char*)xh;
            bf16x8 v0 = *reinterpret_cast<const bf16x8*>(xb + (unsigned)__float_as_int(s0.x) + t * 16);
            bf16x8 v1 = *reinterpret_cast<const bf16x8*>(xb + (unsigned)__float_as_int(s1.x) + t * 16);
            bf16x8 v2 = *reinterpret_cast<const bf16x8*>(xb + (unsigned)__float_as_int(s2.x) + t * 16);
            bf16x8 v3 = *reinterpret_cast<const bf16x8*>(xb + (unsigned)__float_as_int(s3.x) + t * 16);
            float w0 = h1 ? s0.z : s0.y;
            float w1 = h1 ? s1.z : s1.y;
            float w2 = h1 ? s2.z : s2.y;
            float w3 = h1 ? s3.z : s3.y;
#pragma unroll
            for (int q = 0; q < 8; ++q)
                acc[q] += w0 * (float)v0[q] + w1 * (float)v1[q] +
                          w2 * (float)v2[q] + w3 * (float)v3[q];
        }
    }
#pragma unroll
    for (int off = 1; off <= 32; off <<= 1) {
        d0 += __shfl_xor(d0, off);
        d1 += __shfl_xor(d1, off);
    }
#pragma unroll
    for (int q = 0; q < 8; ++q) {
#pragma unroll
        for (int off = G; off < 64; off <<= 1) acc[q] += __shfl_xor(acc[q], off);
    }
    float exs0 = __expf(es0), exs1 = __expf(es1);
    d0 += exs0; d1 += exs1;
    {
        float ws = h1 ? exs1 : exs0;
        bf16x8 v = *reinterpret_cast<const bf16x8*>(xh + (size_t)node * F + t * 8);
#pragma unroll
        for (int q = 0; q < 8; ++q) acc[q] += ws * (float)v[q];
    }
    float inv = 1.0f / ((h1 ? d1 : d0) + EPS_SM);
    float o[8];
#pragma unroll
    for (int q = 0; q < 8; ++q) o[q] = fmaxf(acc[q] * inv + bias[t * 8 + q], 0.f);
    if constexpr (FINAL) {
        // broadcast this node's full 128-ch row via LDS (written by g==0, read by all
        // lanes of the SAME wave -> lgkmcnt ordering suffices, no block barrier)
        if (g == 0) {
#pragma unroll
            for (int q = 0; q < 8; ++q) hbuf[widx][t * 8 + q] = o[q];
        }
        float accl = lb[lane];
#pragma unroll 8
        for (int c = 0; c < 128; ++c) accl += hbuf[widx][c] * lwt[lane][c];
        ((float*)outv)[(size_t)node * 64 + lane] = accl;
    } else if (g == 0) {
        if constexpr (OUTBF16) {
            __bf16* po = (__bf16*)outv + (size_t)node * F + t * 8;
            bf16x8 st;
#pragma unroll
            for (int q = 0; q < 8; ++q) st[q] = (__bf16)o[q];
            *reinterpret_cast<bf16x8*>(po) = st;
        } else {
            float* po = (float*)outv + (size_t)node * F + t * 8;
            *reinterpret_cast<float4*>(po) = make_float4(o[0], o[1], o[2], o[3]);
            *reinterpret_cast<float4*>(po + 4) = make_float4(o[4], o[5], o[6], o[7]);
        }
    }
}

// ---------------- BatchNorm stats (separate pass; 256 blocks = low contention) ----
template <typename T>
__global__ void k_bn_stats(const T* __restrict__ x, float* __restrict__ sums,
                           float* __restrict__ sqs, int n, int f) {
    int c = threadIdx.x;
    float s = 0.f, q = 0.f;
    for (int r = blockIdx.x; r < n; r += gridDim.x) {
        float v = (float)x[(size_t)r * f + c];
        s += v; q += v * v;
    }
    atomicAdd(&sums[c], s);
    atomicAdd(&sqs[c], q);
}

// ---------------- launch ----------------
extern "C" void kernel_launch(void* const* d_in, const int* in_sizes, int n_in,
                              void* d_out, int out_size, void* d_ws, size_t ws_size,
                              hipStream_t stream) {
    const float* x   = (const float*)d_in[0];
    const int*   ei  = (const int*)d_in[1];
    const float* W1  = (const float*)d_in[2];
    const float* as1 = (const float*)d_in[3];
    const float* ad1 = (const float*)d_in[4];
    const float* b1  = (const float*)d_in[5];
    const float* g1  = (const float*)d_in[6];
    const float* be1 = (const float*)d_in[7];
    const float* W2  = (const float*)d_in[8];
    const float* as2 = (const float*)d_in[9];
    const float* ad2 = (const float*)d_in[10];
    const float* b2  = (const float*)d_in[11];
    const float* g2  = (const float*)d_in[12];
    const float* be2 = (const float*)d_in[13];
    const float* W3  = (const float*)d_in[14];
    const float* as3 = (const float*)d_in[15];
    const float* ad3 = (const float*)d_in[16];
    const float* b3  = (const float*)d_in[17];
    const float* lw  = (const float*)d_in[18];
    const float* lb  = (const float*)d_in[19];
    float* outp = (float*)d_out;

    const int n = in_sizes[0] / 128;  // 50000
    const int e = in_sizes[1] / 2;    // 800000

    char* w = (char*)d_ws;
    size_t off = 0;
    auto alloc = [&](size_t bytes) -> void* {
        void* p = w + off;
        off += (bytes + 255) & ~(size_t)255;
        return p;
    };
    __bf16* xhb = (__bf16*)alloc((size_t)n * 256 * 2);
    __bf16* h1b = (__bf16*)alloc((size_t)n * 256 * 2);
    __bf16* h2b = (__bf16*)alloc((size_t)n * 128 * 2);
    int* colb   = (int*)alloc((size_t)n * CAP * 4);  // padded adjacency (25.6 MB)
    __bf16* Wb1 = (__bf16*)alloc(256 * 128 * 2);
    __bf16* Wb2 = (__bf16*)alloc(128 * 256 * 2);
    __bf16* Wb3 = (__bf16*)alloc(128 * 128 * 2);
    int* flag   = (int*)alloc(256);
    float* as1p = (float*)alloc((size_t)n * 2 * 4);  // written by GEMM stores, no zero
    float* ad1p = (float*)alloc((size_t)n * 2 * 4);
    float* as2p = (float*)alloc((size_t)n * 2 * 4);
    float* ad2p = (float*)alloc((size_t)n * 2 * 4);
    float* as3p = (float*)alloc((size_t)n * 2 * 4);
    float* ad3p = (float*)alloc((size_t)n * 2 * 4);
    // ---- contiguous zero block ----
    char* zb_begin = (char*)(w + off);
    int* deg    = (int*)alloc((size_t)n * 4);
    float* bn1  = (float*)alloc(512 * 4);
    float* bn2  = (float*)alloc(512 * 4);
    char* zb_end = (char*)(w + off);
    const int zwords = (int)((zb_end - zb_begin) / 4);

    // init: detect (block 0) + zero (blocks 1..64)
    k_init<<<65, 256, 0, stream>>>(ei, flag, (int*)zb_begin, zwords, e);

    const int ebase = ((e + 255) / 256) * 256;
    const int histblocks = ebase / 256 + 320;  // edge blocks + 81920/256 wconv blocks
    k_hist_wconv<<<histblocks, 256, 0, stream>>>(ei, flag, deg, colb, e, ebase,
                                                 W1, Wb1, W2, Wb2, W3, Wb3);

    const int nwb = (n + 3) / 4;
    const int nrow = (n + 127) / 128;

    // ---- layer 1: 128 -> 2x128 ----
    k_gemm<128, 7, false, 8><<<dim3(2, nrow), 256, 0, stream>>>(
        x, Wb1, xhb, n, 256, nullptr, nullptr, nullptr, as1, ad1, as1p, ad1p);
    k_agg<128, true, false><<<nwb, 256, 0, stream>>>(
        xhb, as1p, ad1p, deg, colb, b1, h1b, n, nullptr, nullptr);
    k_bn_stats<__bf16><<<256, 256, 0, stream>>>(h1b, bn1, bn1 + 256, n, 256);

    // ---- layer 2: 256 -> 2x64 (BN1 inline in GEMM prologue; 64-col tiles) ----
    k_gemm<256, 6, true, 4><<<dim3(2, nrow), 256, 0, stream>>>(
        h1b, Wb2, xhb, n, 128, bn1, g1, be1, as2, ad2, as2p, ad2p);
    k_agg<64, true, false><<<nwb, 256, 0, stream>>>(
        xhb, as2p, ad2p, deg, colb, b2, h2b, n, nullptr, nullptr);
    k_bn_stats<__bf16><<<256, 128, 0, stream>>>(h2b, bn2, bn2 + 256, n, 128);

    // ---- layer 3: 128 -> 2x64 (BN2 inline) + FUSED final linear -> d_out ----
    k_gemm<128, 6, true, 4><<<dim3(2, nrow), 256, 0, stream>>>(
        h2b, Wb3, xhb, n, 128, bn2, g2, be2, as3, ad3, as3p, ad3p);
    k_agg<64, false, true><<<nwb, 256, 0, stream>>>(
        xhb, as3p, ad3p, deg, colb, b3, outp, n, lw, lb);
}

// Round 13
// 459.014 us; speedup vs baseline: 1.0652x; 1.0652x over previous
//
#include <hip/hip_runtime.h>
#include <hip/hip_bf16.h>

#define NEG_SLOPE 0.2f
#define EPS_BN 1e-5f
#define EPS_SM 1e-16f
#define CAP 128  // padded adjacency row capacity (Poisson(17): P(deg>128) ~ 0; clamped anyway)

typedef __bf16 bf16x8 __attribute__((ext_vector_type(8)));
typedef __bf16 bf16x4 __attribute__((ext_vector_type(4)));
typedef float floatx4 __attribute__((ext_vector_type(4)));

__device__ __forceinline__ float leaky(float x) { return x > 0.f ? x : NEG_SLOPE * x; }

// ---- init: block 0 = edge dtype detect (no atomics, no pre-zero); blocks 1.. = zero ----
__global__ void k_init(const int* __restrict__ ei, int* __restrict__ flag,
                       int* __restrict__ zbase, int zwords, int e) {
    if (blockIdx.x == 0) {
        __shared__ int cnt_s[256];
        int i = threadIdx.x;  // pairs 0..255
        int nz = (2 * i + 1 < 2 * e && ei[2 * i + 1] != 0) ? 1 : 0;
        cnt_s[i] = nz;
        __syncthreads();
        for (int off = 128; off > 0; off >>= 1) {
            if (i < off) cnt_s[i] += cnt_s[i + off];
            __syncthreads();
        }
        if (i == 0) *flag = (cnt_s[0] < 128) ? 1 : 0;  // 1 => int64 layout
        return;
    }
    int g = (blockIdx.x - 1) * 256 + threadIdx.x;
    int stride = (gridDim.x - 1) * 256;
    for (int k = g; k < zwords; k += stride) zbase[k] = 0;
}

// ---- hist + DIRECT scatter (rank from atomic) + weight convert in grid tail ----
__global__ void k_hist_wconv(const int* __restrict__ ei, const int* __restrict__ flag,
                             int* __restrict__ deg, int* __restrict__ col, int e, int ebase,
                             const float* __restrict__ W1, __bf16* __restrict__ Wb1,
                             const float* __restrict__ W2, __bf16* __restrict__ Wb2,
                             const float* __restrict__ W3, __bf16* __restrict__ Wb3) {
    int g = threadIdx.x + blockIdx.x * blockDim.x;
    if (g < e) {
        bool is64 = (*flag) != 0;
        int s = is64 ? ei[2 * g] : ei[g];
        int d = is64 ? ei[2 * (e + g)] : ei[e + g];
        int r = atomicAdd(&deg[d], 1);
        if (r < CAP) col[((size_t)d << 7) + r] = s;
    } else {
        int idx = g - ebase;
        if (idx >= 0 && idx < 32768) {          // W1: K=128, M=256
            int mm = idx >> 7, kk = idx & 127;
            Wb1[idx] = (__bf16)W1[(size_t)kk * 256 + mm];
        } else if (idx < 65536) {               // W2: K=256, M=128
            int i2 = idx - 32768;
            int mm = i2 >> 8, kk = i2 & 255;
            Wb2[i2] = (__bf16)W2[(size_t)kk * 128 + mm];
        } else if (idx < 81920) {               // W3: K=128, M=128
            int i3 = idx - 65536;
            int mm = i3 >> 7, kk = i3 & 127;
            Wb3[i3] = (__bf16)W3[(size_t)kk * 128 + mm];
        }
    }
}

// ---- bf16 MFMA GEMM, 128-row x (NT*16)-col tile, inline BN prep + attn dots.
//      Each block covers ONE complete head -> attn dots are complete: plain stores.
template <int K, int LC, bool BF16IN, int NT>
__global__ __launch_bounds__(256) void k_gemm(const void* __restrict__ Ain,
                                              const __bf16* __restrict__ Bt,
                                              __bf16* __restrict__ Cb, int n, int M,
                                              const float* __restrict__ bnsums,
                                              const float* __restrict__ gam,
                                              const float* __restrict__ bet,
                                              const float* __restrict__ att_s,
                                              const float* __restrict__ att_d,
                                              float* __restrict__ asrc,
                                              float* __restrict__ adst) {
    __shared__ __align__(16) __bf16 As[128][72];
    __shared__ __align__(16) __bf16 Bs[NT * 16][72];
    __shared__ float sc_lds[K], sh_lds[K];
    const int row0 = blockIdx.y * 128, col0 = blockIdx.x * (NT * 16);
    const int lane = threadIdx.x & 63, w = threadIdx.x >> 6;
    const int m = lane & 15, quad = lane >> 4;

    if (bnsums) {
        for (int c = threadIdx.x; c < K; c += 256) {
            float mean = bnsums[c] / n;
            float var = bnsums[256 + c] / n - mean * mean;
            float sc = gam[c] * rsqrtf(var + EPS_BN);
            sc_lds[c] = sc;
            sh_lds[c] = bet[c] - mean * sc;
        }
        __syncthreads();
    }

    floatx4 acc[2][NT];
#pragma unroll
    for (int i = 0; i < 2; ++i)
#pragma unroll
        for (int j = 0; j < NT; ++j) acc[i][j] = (floatx4)0.f;

    const int sr = threadIdx.x >> 1;        // A-stage: 0..127
    const int sk = (threadIdx.x & 1) * 32;

    for (int kc = 0; kc < K; kc += 64) {
        {
            int grow = row0 + sr;
            if (grow < n) {
                if (BF16IN) {
                    const __bf16* p = (const __bf16*)Ain + (size_t)grow * K + kc + sk;
#pragma unroll
                    for (int q = 0; q < 4; ++q) {
                        bf16x8 vv = *reinterpret_cast<const bf16x8*>(p + q * 8);
                        if (bnsums) {
                            int c = kc + sk + q * 8;
                            bf16x8 r;
#pragma unroll
                            for (int e2 = 0; e2 < 8; ++e2)
                                r[e2] = (__bf16)((float)vv[e2] * sc_lds[c + e2] + sh_lds[c + e2]);
                            vv = r;
                        }
                        *reinterpret_cast<bf16x8*>(&As[sr][sk + q * 8]) = vv;
                    }
                } else {
                    const float* p = (const float*)Ain + (size_t)grow * K + kc + sk;
#pragma unroll
                    for (int q = 0; q < 8; ++q) {
                        float4 v = *reinterpret_cast<const float4*>(p + q * 4);
                        bf16x4 cv = {(__bf16)v.x, (__bf16)v.y, (__bf16)v.z, (__bf16)v.w};
                        *reinterpret_cast<bf16x4*>(&As[sr][sk + q * 4]) = cv;
                    }
                }
            } else {
#pragma unroll
                for (int q = 0; q < 4; ++q)
                    *reinterpret_cast<bf16x8*>(&As[sr][sk + q * 8]) = (bf16x8)(__bf16)0.f;
            }
        }
        if (NT == 8) {
            const __bf16* p = Bt + (size_t)(col0 + sr) * K + kc + sk;
#pragma unroll
            for (int q = 0; q < 4; ++q)
                *reinterpret_cast<bf16x8*>(&Bs[sr][sk + q * 8]) =
                    *reinterpret_cast<const bf16x8*>(p + q * 8);
        } else {  // NT==4: 64 B-rows, 16 bf16 per thread
            int sr4 = threadIdx.x >> 2, sk4 = (threadIdx.x & 3) * 16;
            const __bf16* p = Bt + (size_t)(col0 + sr4) * K + kc + sk4;
            *reinterpret_cast<bf16x8*>(&Bs[sr4][sk4]) = *reinterpret_cast<const bf16x8*>(p);
            *reinterpret_cast<bf16x8*>(&Bs[sr4][sk4 + 8]) = *reinterpret_cast<const bf16x8*>(p + 8);
        }
        __syncthreads();
#pragma unroll
        for (int ks = 0; ks < 64; ks += 32) {
            bf16x8 a0 = *reinterpret_cast<const bf16x8*>(&As[w * 32 + m][ks + quad * 8]);
            bf16x8 a1 = *reinterpret_cast<const bf16x8*>(&As[w * 32 + 16 + m][ks + quad * 8]);
#pragma unroll
            for (int nt = 0; nt < NT; ++nt) {
                bf16x8 b = *reinterpret_cast<const bf16x8*>(&Bs[nt * 16 + m][ks + quad * 8]);
                acc[0][nt] = __builtin_amdgcn_mfma_f32_16x16x32_bf16(a0, b, acc[0][nt], 0, 0, 0);
                acc[1][nt] = __builtin_amdgcn_mfma_f32_16x16x32_bf16(a1, b, acc[1][nt], 0, 0, 0);
            }
        }
        __syncthreads();
    }
#pragma unroll
    for (int mt = 0; mt < 2; ++mt)
#pragma unroll
        for (int nt = 0; nt < NT; ++nt)
#pragma unroll
            for (int r = 0; r < 4; ++r) {
                int row = row0 + w * 32 + mt * 16 + quad * 4 + r;
                if (row < n) Cb[(size_t)row * M + col0 + nt * 16 + m] = (__bf16)acc[mt][nt][r];
            }
    // fused attention dots (single complete head per block -> plain store)
    {
        float asv[NT], adv[NT];
#pragma unroll
        for (int nt = 0; nt < NT; ++nt) {
            int c = col0 + nt * 16 + m;
            asv[nt] = att_s[c];
            adv[nt] = att_d[c];
        }
        const int h = (col0 >> LC) & 1;
#pragma unroll
        for (int mt = 0; mt < 2; ++mt)
#pragma unroll
            for (int r = 0; r < 4; ++r) {
                int row = row0 + w * 32 + mt * 16 + quad * 4 + r;
                float pa = 0.f, pb = 0.f;
#pragma unroll
                for (int nt = 0; nt < NT; ++nt) {
                    float v = acc[mt][nt][r];
                    pa += v * asv[nt];
                    pb += v * adv[nt];
                }
#pragma unroll
                for (int off = 1; off <= 8; off <<= 1) {
                    pa += __shfl_xor(pa, off);
                    pb += __shfl_xor(pb, off);
                }
                if (m == 0 && row < n) {
                    asrc[2 * row + h] = pa;
                    adst[2 * row + h] = pb;
                }
            }
    }
}

// ---- final linear via MFMA: out[n,64](f32) = A[n,128](f32) @ lw[128,64] + lb ----
__global__ __launch_bounds__(256) void k_lin(const float* __restrict__ A,
                                             const float* __restrict__ lw,
                                             const float* __restrict__ lb,
                                             float* __restrict__ out, int n) {
    __shared__ __align__(16) __bf16 Ahi[64][136];
    __shared__ __align__(16) __bf16 Alo[64][136];
    __shared__ __align__(16) __bf16 Bhi[64][136];
    const int row0 = blockIdx.x * 64;
    const int lane = threadIdx.x & 63, w = threadIdx.x >> 6;
    const int m = lane & 15, quad = lane >> 4;
    floatx4 acc[4];
#pragma unroll
    for (int i = 0; i < 4; ++i) acc[i] = (floatx4)0.f;
    {
        int sr = threadIdx.x >> 2, sk0 = (threadIdx.x & 3) * 32;
        int grow = row0 + sr;
#pragma unroll
        for (int q = 0; q < 8; ++q) {
            float4 v = make_float4(0.f, 0.f, 0.f, 0.f);
            if (grow < n) v = *reinterpret_cast<const float4*>(A + (size_t)grow * 128 + sk0 + q * 4);
            float vv[4] = {v.x, v.y, v.z, v.w};
#pragma unroll
            for (int i = 0; i < 4; ++i) {
                __bf16 h = (__bf16)vv[i];
                Ahi[sr][sk0 + q * 4 + i] = h;
                Alo[sr][sk0 + q * 4 + i] = (__bf16)(vv[i] - (float)h);
            }
        }
    }
    {
        int k0 = threadIdx.x >> 1, m0 = (threadIdx.x & 1) * 32;
#pragma unroll
        for (int q = 0; q < 8; ++q) {
            float4 v = *reinterpret_cast<const float4*>(lw + (size_t)k0 * 64 + m0 + q * 4);
            float vv[4] = {v.x, v.y, v.z, v.w};
#pragma unroll
            for (int i = 0; i < 4; ++i) Bhi[m0 + q * 4 + i][k0] = (__bf16)vv[i];
        }
    }
    __syncthreads();
#pragma unroll
    for (int ks = 0; ks < 128; ks += 32) {
        bf16x8 ah = *reinterpret_cast<const bf16x8*>(&Ahi[w * 16 + m][ks + quad * 8]);
        bf16x8 al = *reinterpret_cast<const bf16x8*>(&Alo[w * 16 + m][ks + quad * 8]);
#pragma unroll
        for (int nt = 0; nt < 4; ++nt) {
            bf16x8 bh = *reinterpret_cast<const bf16x8*>(&Bhi[nt * 16 + m][ks + quad * 8]);
            acc[nt] = __builtin_amdgcn_mfma_f32_16x16x32_bf16(ah, bh, acc[nt], 0, 0, 0);
            acc[nt] = __builtin_amdgcn_mfma_f32_16x16x32_bf16(al, bh, acc[nt], 0, 0, 0);
        }
    }
#pragma unroll
    for (int nt = 0; nt < 4; ++nt)
#pragma unroll
        for (int r = 0; r < 4; ++r) {
            int row = row0 + w * 16 + quad * 4 + r;
            int c = nt * 16 + m;
            if (row < n) out[(size_t)row * 64 + c] = acc[nt][r] + lb[c];
        }
}

// ---- GAT aggregation: grouped gather, 4 slots in flight, padded-CSR ----
template <int C, bool OUTBF16>
__global__ __launch_bounds__(256) void k_agg(const __bf16* __restrict__ xh,
                                             const float* __restrict__ asrc,
                                             const float* __restrict__ adst,
                                             const int* __restrict__ degv,
                                             const int* __restrict__ col,
                                             const float* __restrict__ bias,
                                             void* __restrict__ outv, int n) {
    constexpr int F = 2 * C;          // bf16 per row (256 or 128)
    constexpr int G = F / 8;          // lanes per edge (32 or 16)
    constexpr int NG = 64 / G;        // edges per wave-step (2 or 4)
    constexpr int GSH = (G == 32) ? 5 : 4;
    __shared__ float4 slots[4][80];   // 64 + 16 zero-pad for 4-deep unroll overrun
    const int widx = threadIdx.x >> 6;
    const int node = blockIdx.x * 4 + widx;
    const int lane = threadIdx.x & 63;
    if (node >= n) return;
    const int t = lane & (G - 1);
    const int g = lane >> GSH;
    const bool h1 = (t * 8) >= C;
    if (lane >= 48) slots[widx][lane + 16] = make_float4(0.f, 0.f, 0.f, 0.f);
    const int* crow = col + ((size_t)node << 7);
    const int deg = min(degv[node], CAP);
    const float2 adv = *reinterpret_cast<const float2*>(adst + 2 * node);
    const float2 asv = *reinterpret_cast<const float2*>(asrc + 2 * node);
    const float es0 = leaky(asv.x + adv.x), es1 = leaky(asv.y + adv.y);
    float acc[8] = {};
    float d0 = 0.f, d1 = 0.f;
    for (int base = 0; base < deg; base += 64) {
        const int cnt = min(64, deg - base);
        float4 sv = make_float4(0.f, 0.f, 0.f, 0.f);
        if (lane < cnt) {
            int s = crow[base + lane];
            float2 av = *reinterpret_cast<const float2*>(asrc + 2 * s);
            float w0 = __expf(leaky(av.x + adv.x));
            float w1 = __expf(leaky(av.y + adv.y));
            d0 += w0; d1 += w1;
            sv = make_float4(__int_as_float(s * (F * 2)), w0, w1, 0.f);
        }
        slots[widx][lane] = sv;  // wave-synchronous; zero weights beyond cnt
        for (int j = g; j < cnt; j += 4 * NG) {
            float4 s0 = slots[widx][j];
            float4 s1 = slots[widx][j + NG];
            float4 s2 = slots[widx][j + 2 * NG];
            float4 s3 = slots[widx][j + 3 * NG];
            const char* xb = (const char*)xh;
            bf16x8 v0 = *reinterpret_cast<const bf16x8*>(xb + (unsigned)__float_as_int(s0.x) + t * 16);
            bf16x8 v1 = *reinterpret_cast<const bf16x8*>(xb + (unsigned)__float_as_int(s1.x) + t * 16);
            bf16x8 v2 = *reinterpret_cast<const bf16x8*>(xb + (unsigned)__float_as_int(s2.x) + t * 16);
            bf16x8 v3 = *reinterpret_cast<const bf16x8*>(xb + (unsigned)__float_as_int(s3.x) + t * 16);
            float w0 = h1 ? s0.z : s0.y;
            float w1 = h1 ? s1.z : s1.y;
            float w2 = h1 ? s2.z : s2.y;
            float w3 = h1 ? s3.z : s3.y;
#pragma unroll
            for (int q = 0; q < 8; ++q)
                acc[q] += w0 * (float)v0[q] + w1 * (float)v1[q] +
                          w2 * (float)v2[q] + w3 * (float)v3[q];
        }
    }
#pragma unroll
    for (int off = 1; off <= 32; off <<= 1) {
        d0 += __shfl_xor(d0, off);
        d1 += __shfl_xor(d1, off);
    }
#pragma unroll
    for (int q = 0; q < 8; ++q) {
#pragma unroll
        for (int off = G; off < 64; off <<= 1) acc[q] += __shfl_xor(acc[q], off);
    }
    float exs0 = __expf(es0), exs1 = __expf(es1);
    d0 += exs0; d1 += exs1;
    {
        float ws = h1 ? exs1 : exs0;
        bf16x8 v = *reinterpret_cast<const bf16x8*>(xh + (size_t)node * F + t * 8);
#pragma unroll
        for (int q = 0; q < 8; ++q) acc[q] += ws * (float)v[q];
    }
    float inv = 1.0f / ((h1 ? d1 : d0) + EPS_SM);
    float o[8];
#pragma unroll
    for (int q = 0; q < 8; ++q) o[q] = fmaxf(acc[q] * inv + bias[t * 8 + q], 0.f);
    if (g == 0) {
        if constexpr (OUTBF16) {
            __bf16* po = (__bf16*)outv + (size_t)node * F + t * 8;
            bf16x8 st;
#pragma unroll
            for (int q = 0; q < 8; ++q) st[q] = (__bf16)o[q];
            *reinterpret_cast<bf16x8*>(po) = st;
        } else {
            float* po = (float*)outv + (size_t)node * F + t * 8;
            *reinterpret_cast<float4*>(po) = make_float4(o[0], o[1], o[2], o[3]);
            *reinterpret_cast<float4*>(po + 4) = make_float4(o[4], o[5], o[6], o[7]);
        }
    }
}

// ---------------- BatchNorm stats (separate pass; 256 blocks = low contention) ----
template <typename T>
__global__ void k_bn_stats(const T* __restrict__ x, float* __restrict__ sums,
                           float* __restrict__ sqs, int n, int f) {
    int c = threadIdx.x;
    float s = 0.f, q = 0.f;
    for (int r = blockIdx.x; r < n; r += gridDim.x) {
        float v = (float)x[(size_t)r * f + c];
        s += v; q += v * v;
    }
    atomicAdd(&sums[c], s);
    atomicAdd(&sqs[c], q);
}

// ---------------- launch ----------------
extern "C" void kernel_launch(void* const* d_in, const int* in_sizes, int n_in,
                              void* d_out, int out_size, void* d_ws, size_t ws_size,
                              hipStream_t stream) {
    const float* x   = (const float*)d_in[0];
    const int*   ei  = (const int*)d_in[1];
    const float* W1  = (const float*)d_in[2];
    const float* as1 = (const float*)d_in[3];
    const float* ad1 = (const float*)d_in[4];
    const float* b1  = (const float*)d_in[5];
    const float* g1  = (const float*)d_in[6];
    const float* be1 = (const float*)d_in[7];
    const float* W2  = (const float*)d_in[8];
    const float* as2 = (const float*)d_in[9];
    const float* ad2 = (const float*)d_in[10];
    const float* b2  = (const float*)d_in[11];
    const float* g2  = (const float*)d_in[12];
    const float* be2 = (const float*)d_in[13];
    const float* W3  = (const float*)d_in[14];
    const float* as3 = (const float*)d_in[15];
    const float* ad3 = (const float*)d_in[16];
    const float* b3  = (const float*)d_in[17];
    const float* lw  = (const float*)d_in[18];
    const float* lb  = (const float*)d_in[19];
    float* outp = (float*)d_out;

    const int n = in_sizes[0] / 128;  // 50000
    const int e = in_sizes[1] / 2;    // 800000

    char* w = (char*)d_ws;
    size_t off = 0;
    auto alloc = [&](size_t bytes) -> void* {
        void* p = w + off;
        off += (bytes + 255) & ~(size_t)255;
        return p;
    };
    __bf16* xhb = (__bf16*)alloc((size_t)n * 256 * 2);
    __bf16* h1b = (__bf16*)alloc((size_t)n * 256 * 2);
    __bf16* h2b = (__bf16*)alloc((size_t)n * 128 * 2);
    float*  h3f = (float*)alloc((size_t)n * 128 * 4);
    int* colb   = (int*)alloc((size_t)n * CAP * 4);  // padded adjacency (25.6 MB)
    __bf16* Wb1 = (__bf16*)alloc(256 * 128 * 2);
    __bf16* Wb2 = (__bf16*)alloc(128 * 256 * 2);
    __bf16* Wb3 = (__bf16*)alloc(128 * 128 * 2);
    int* flag   = (int*)alloc(256);
    float* as1p = (float*)alloc((size_t)n * 2 * 4);  // written by GEMM stores, no zero
    float* ad1p = (float*)alloc((size_t)n * 2 * 4);
    float* as2p = (float*)alloc((size_t)n * 2 * 4);
    float* ad2p = (float*)alloc((size_t)n * 2 * 4);
    float* as3p = (float*)alloc((size_t)n * 2 * 4);
    float* ad3p = (float*)alloc((size_t)n * 2 * 4);
    // ---- contiguous zero block ----
    char* zb_begin = (char*)(w + off);
    int* deg    = (int*)alloc((size_t)n * 4);
    float* bn1  = (float*)alloc(512 * 4);
    float* bn2  = (float*)alloc(512 * 4);
    char* zb_end = (char*)(w + off);
    const int zwords = (int)((zb_end - zb_begin) / 4);

    // init: detect (block 0) + zero (blocks 1..64)
    k_init<<<65, 256, 0, stream>>>(ei, flag, (int*)zb_begin, zwords, e);

    const int ebase = ((e + 255) / 256) * 256;
    const int histblocks = ebase / 256 + 320;  // edge blocks + 81920/256 wconv blocks
    k_hist_wconv<<<histblocks, 256, 0, stream>>>(ei, flag, deg, colb, e, ebase,
                                                 W1, Wb1, W2, Wb2, W3, Wb3);

    const int nwb = (n + 3) / 4;
    const int nrow = (n + 127) / 128;

    // ---- layer 1: 128 -> 2x128 ----
    k_gemm<128, 7, false, 8><<<dim3(2, nrow), 256, 0, stream>>>(
        x, Wb1, xhb, n, 256, nullptr, nullptr, nullptr, as1, ad1, as1p, ad1p);
    k_agg<128, true><<<nwb, 256, 0, stream>>>(xhb, as1p, ad1p, deg, colb, b1, h1b, n);
    k_bn_stats<__bf16><<<256, 256, 0, stream>>>(h1b, bn1, bn1 + 256, n, 256);

    // ---- layer 2: 256 -> 2x64 (BN1 inline in GEMM prologue; 64-col tiles) ----
    k_gemm<256, 6, true, 4><<<dim3(2, nrow), 256, 0, stream>>>(
        h1b, Wb2, xhb, n, 128, bn1, g1, be1, as2, ad2, as2p, ad2p);
    k_agg<64, true><<<nwb, 256, 0, stream>>>(xhb, as2p, ad2p, deg, colb, b2, h2b, n);
    k_bn_stats<__bf16><<<256, 128, 0, stream>>>(h2b, bn2, bn2 + 256, n, 128);

    // ---- layer 3: 128 -> 2x64 (BN2 inline) ----
    k_gemm<128, 6, true, 4><<<dim3(2, nrow), 256, 0, stream>>>(
        h2b, Wb3, xhb, n, 128, bn2, g2, be2, as3, ad3, as3p, ad3p);
    k_agg<64, false><<<nwb, 256, 0, stream>>>(xhb, as3p, ad3p, deg, colb, b3, h3f, n);

    // ---- final linear ----
    k_lin<<<(n + 63) / 64, 256, 0, stream>>>(h3f, lw, lb, outp, n);
}